// Round 6
// baseline (1141.901 us; speedup 1.0000x reference)
//
#include <hip/hip_runtime.h>

#define BN 64
#define SN 128
#define TN 64
#define FN 100
#define G3 300

__device__ __forceinline__ float rl(float v, int l){
  return __int_as_float(__builtin_amdgcn_readlane(__float_as_int(v), l));
}
__device__ __forceinline__ float fast_exp(float x){        // e^x
  return __builtin_amdgcn_exp2f(x * 1.44269504088896341f);
}
__device__ __forceinline__ float fast_tanh(float x){
  float e = __builtin_amdgcn_exp2f(x * 2.88539008177792681f);
  return 1.0f - 2.0f * __builtin_amdgcn_rcpf(1.0f + e);
}
__device__ __forceinline__ float fast_sig(float x){
  return __builtin_amdgcn_rcpf(1.0f + __builtin_amdgcn_exp2f(-1.44269504088896341f * x));
}

// ---------------------------------------------------------------------------
// Kernel 1: xw[row][o] = sum_f x[row][f] * W[f][o] + b[o]   (rows = B*S*T)
// Round-0 v1 structure (445us known-good). The LDS-broadcast family (v2-v5)
// bottomed out at 470-660us: R=1 is LDS-writeback-bound (~416us floor),
// larger R either spills (v4) or eats exposed load latency from the
// sched_barrier fences needed to prevent the spill (v5, 538us).
// W accessed with wave-uniform indices -> scalarized to s_load; 10k FMA/thread.
// ---------------------------------------------------------------------------
__global__ __launch_bounds__(256, 3) void k_xw(
    const float* __restrict__ x, const float* __restrict__ W,
    const float* __restrict__ b, float* __restrict__ xw)
{
  const long row = (long)blockIdx.x * 256 + threadIdx.x;
  const float4* xr4 = reinterpret_cast<const float4*>(x + row * FN);
  float acc[FN];
  #pragma unroll
  for (int j = 0; j < FN; j++) acc[j] = b[j];
  #pragma unroll 1
  for (int fc = 0; fc < 25; fc++){
    float4 xv = xr4[fc];
    const float* Wr = W + fc * 4 * FN;
    #pragma unroll
    for (int j = 0; j < FN; j++) acc[j] = fmaf(xv.x, Wr[j],        acc[j]);
    #pragma unroll
    for (int j = 0; j < FN; j++) acc[j] = fmaf(xv.y, Wr[FN + j],   acc[j]);
    #pragma unroll
    for (int j = 0; j < FN; j++) acc[j] = fmaf(xv.z, Wr[2*FN + j], acc[j]);
    #pragma unroll
    for (int j = 0; j < FN; j++) acc[j] = fmaf(xv.w, Wr[3*FN + j], acc[j]);
  }
  float4* op = reinterpret_cast<float4*>(xw + row * FN);
  #pragma unroll
  for (int j = 0; j < 25; j++)
    op[j] = make_float4(acc[4*j], acc[4*j+1], acc[4*j+2], acc[4*j+3]);
}

// ---------------------------------------------------------------------------
// Kernel 2: per-batch sequential scan.
// v2: 1024 threads (16 waves -> 4 waves/SIMD, was 2). Round-4 counters:
// active-CU VALU issue ~42%, 9270 cyc/step vs ~2-4k issue floor ->
// latency-bound at 2 waves/SIMD. All wide phases redistributed 2x:
//  A/D: 8 f-slices of 13 (zero-padded to 104); B: 16 f-slices of 7;
//  C: 8 t-slices of 8; partials -> part[700][9] (stride 9 odd -> 2-way
//  bank aliasing only, free).
// DMA drain: explicit vmcnt(0) before bar2 (consumption point of xwbuf is
// phase B after bar2) -> DMA latency window spans D+GRU+A of previous step.
// ---------------------------------------------------------------------------
__global__ __launch_bounds__(1024, 1) void k_scan(
    const float* __restrict__ x, const float* __restrict__ xw,
    const float* __restrict__ Wc, const float* __restrict__ u,
    const float* __restrict__ Wx, const float* __restrict__ Wh,
    const float* __restrict__ bg, float* __restrict__ out)
{
  const int b    = blockIdx.x;
  const int tid  = threadIdx.x;
  const int lane = tid & 63;
  const int wid  = tid >> 6;         // 0..15

  // phase A/D layout: 8 f-slices of 13 x 128 "g-threads"
  const int gth = tid & 127;
  const int fsl = tid >> 7;          // 0..7
  // phase B layout: 64 t x 16 f-slices of 7
  const int tB  = tid >> 4;          // 0..63
  const int fsB = tid & 15;          // 0..15
  // phase C layout: 100 f x 8 t-slices of 8
  const bool fCv = (tid & 127) < FN;
  const int fC  = fCv ? (tid & 127) : (FN - 1);
  const int tsC = tid >> 7;          // 0..7

  __shared__ __align__(16) float xwbuf[2][TN*FN + 16];   // +16 pad for tail-slice overreads
  __shared__ float part[700][9];    // 8 partial cols + 1 pad (odd stride -> 2-way banks)
  __shared__ float h_lds[128];
  __shared__ float c_lds[128];
  __shared__ float att_lds[128];
  __shared__ __align__(16) float ea_lds[64];
  __shared__ float dpart[16];

  // ---- per-thread weight registers ----
  // outputs o = gth + 128*p, p<5; o<300 -> gx (Wx), 300<=o<600 -> gh (Wh)
  float wr[13][5];
  float wcr[13];
  const bool hasC = (gth >= 28);
  const int  co   = hasC ? gth - 28 : 0;
  #pragma unroll
  for (int j = 0; j < 13; j++){
    const int f = fsl*13 + j;                    // f in 0..103; pads guarded to 0
    #pragma unroll
    for (int p = 0; p < 5; p++){
      const int o = gth + 128*p;
      wr[j][p] = (o < 600 && f < FN)
               ? ((o < 300) ? Wx[f*G3 + o] : Wh[f*G3 + (o-300)]) : 0.0f;
    }
    wcr[j] = (hasC && f < FN) ? Wc[f*FN + co] : 0.0f;
  }
  // u slices for phase B (zero-padded past f=99)
  float ur[7];
  #pragma unroll
  for (int i = 0; i < 7; i++){
    const int f = fsB*7 + i;
    ur[i] = (f < FN) ? u[f] : 0.0f;
  }
  // init LDS (h=0; zero pads so garbage never becomes NaN through tanh;
  // h_lds/att_lds[100..127] stay 0 forever -> padded f-slices contribute 0)
  if (tid < 128){ h_lds[tid] = 0.0f; c_lds[tid] = 0.0f; att_lds[tid] = 0.0f; }
  if (tid < 16){ xwbuf[0][TN*FN + tid] = 0.0f; xwbuf[1][TN*FN + tid] = 0.0f; }
  __syncthreads();

  const long tileStride = (long)TN*FN;                 // 6400
  const float* xw_base = xw + (long)b*SN*tileStride;
  const float* x_base  = x  + (long)b*SN*tileStride;

  auto issue_xw_dma = [&](int s, int bi){
    const char* g = (const char*)(xw_base + (long)s*tileStride);
    char* l = (char*)(&xwbuf[bi][0]);
    #pragma unroll
    for (int r = 0; r < 2; r++){
      const int chunk = (r*16 + wid) * 1024;
      if (chunk < 25600){
        __builtin_amdgcn_global_load_lds(
          (const __attribute__((address_space(1))) unsigned int*)(g + chunk + lane*16),
          (__attribute__((address_space(3))) unsigned int*)(l + chunk),
          16, 0, 0);
      }
    }
  };

#define ISSUE_X(sp, arr) do { \
    const float* gp_ = x_base + (long)(sp)*tileStride + (long)tsC*(8*FN) + fC; \
    _Pragma("unroll") \
    for (int k_ = 0; k_ < 8; k_++) arr[k_] = gp_[k_*FN]; \
  } while(0)

  float xcur[8], xnxt[8];
  issue_xw_dma(0, 0);
  ISSUE_X(0, xcur);

  for (int s = 0; s < SN; s++){
    // ---- phase A: c = h @ Wc ----
    float hp = h_lds[fsl*13 + (lane < 13 ? lane : 0)];  // old h, packed for readlane
    float accC = 0.0f;
    #pragma unroll
    for (int j = 0; j < 13; j++) accC = fmaf(rl(hp, j), wcr[j], accC);
    if (hasC) part[600 + co][fsl] = accC;
    __syncthreads();                                    // bar1

    if (tid < FN){
      const float* pr = part[600 + tid];
      c_lds[tid] = ((pr[0]+pr[1]) + (pr[2]+pr[3]))
                 + ((pr[4]+pr[5]) + (pr[6]+pr[7]));
    }
    __builtin_amdgcn_s_waitcnt(0x0F70);                 // vmcnt(0): xw DMA in LDS
    __syncthreads();                                    // bar2

    // ---- phase B: ait[t] = sum_f u[f]*tanh(xw + c), ea = exp(ait) ----
    {
      const float* cp = &c_lds[fsB*7];
      const float* xp = &xwbuf[s&1][tB*FN + fsB*7];
      float accB = 0.0f;
      #pragma unroll
      for (int i = 0; i < 7; i++)
        accB = fmaf(fast_tanh(xp[i] + cp[i]), ur[i], accB);
      accB += __shfl_xor(accB, 1);
      accB += __shfl_xor(accB, 2);
      accB += __shfl_xor(accB, 4);
      accB += __shfl_xor(accB, 8);
      float ea = fast_exp(accB);
      if (fsB == 0) ea_lds[tB] = ea;
      float dsum = ea;                                  // wave-level denom partial
      dsum += __shfl_xor(dsum, 16);
      dsum += __shfl_xor(dsum, 32);
      if (lane == 0) dpart[wid] = dsum;
    }
    __syncthreads();                                    // bar3

    // ---- phase C: attended partials (unnormalized) ----
    {
      const float4* eap = reinterpret_cast<const float4*>(&ea_lds[tsC*8]);
      float4 e0 = eap[0], e1 = eap[1];
      float a = 0.0f;
      a = fmaf(xcur[0], e0.x, a); a = fmaf(xcur[1], e0.y, a);
      a = fmaf(xcur[2], e0.z, a); a = fmaf(xcur[3], e0.w, a);
      a = fmaf(xcur[4], e1.x, a); a = fmaf(xcur[5], e1.y, a);
      a = fmaf(xcur[6], e1.z, a); a = fmaf(xcur[7], e1.w, a);
      if (fCv) part[600 + fC][tsC] = a;                 // overlay (c partials are dead)
    }
    __syncthreads();                                    // bar4

    if (tid < FN){
      float den = ((dpart[0]+dpart[1])+(dpart[2]+dpart[3]))
                + ((dpart[4]+dpart[5])+(dpart[6]+dpart[7]))
                + ((dpart[8]+dpart[9])+(dpart[10]+dpart[11]))
                + ((dpart[12]+dpart[13])+(dpart[14]+dpart[15])) + 1e-7f;
      const float* pr = part[600 + tid];
      float sm = ((pr[0]+pr[1]) + (pr[2]+pr[3]))
               + ((pr[4]+pr[5]) + (pr[6]+pr[7]));
      att_lds[tid] = sm / den;
    }
    __syncthreads();                                    // bar5

    // ---- prefetch next tiles (phase D + GRU + next A hide the latency) ----
    {
      const int sp = (s+1 < SN) ? s+1 : s;
      issue_xw_dma(sp, (s+1)&1);
      ISSUE_X(sp, xnxt);
    }

    // ---- phase D: gx = att@Wx, gh = h@Wh (register weights + readlane) ----
    {
      float attp = att_lds[fsl*13 + (lane < 13 ? lane : 0)];
      const bool p2x = (gth < 44);                      // p=2 output is gx iff gth<44
      float a0=0.f, a1=0.f, a2=0.f, a3=0.f, a4=0.f;
      #pragma unroll
      for (int j = 0; j < 13; j++){
        float sa = rl(attp, j);
        float sh = rl(hp, j);
        float s2 = p2x ? sa : sh;
        a0 = fmaf(sa, wr[j][0], a0);
        a1 = fmaf(sa, wr[j][1], a1);
        a2 = fmaf(s2, wr[j][2], a2);
        a3 = fmaf(sh, wr[j][3], a3);
        a4 = fmaf(sh, wr[j][4], a4);
      }
      part[gth      ][fsl] = a0;
      part[gth + 128][fsl] = a1;
      part[gth + 256][fsl] = a2;
      part[gth + 384][fsl] = a3;
      if (gth < 88) part[gth + 512][fsl] = a4;
    }
    __syncthreads();                                    // bar6

    // ---- GRU update ----
    if (tid < FN){
      const int g = tid;
      const float* p0 = part[g];
      const float* p1 = part[100+g];
      const float* p2 = part[200+g];
      const float* p3 = part[300+g];
      const float* p4 = part[400+g];
      const float* p5 = part[500+g];
      float gxz = ((p0[0]+p0[1])+(p0[2]+p0[3]))+((p0[4]+p0[5])+(p0[6]+p0[7])) + bg[g];
      float gxr = ((p1[0]+p1[1])+(p1[2]+p1[3]))+((p1[4]+p1[5])+(p1[6]+p1[7])) + bg[100+g];
      float gxh = ((p2[0]+p2[1])+(p2[2]+p2[3]))+((p2[4]+p2[5])+(p2[6]+p2[7])) + bg[200+g];
      float ghz = ((p3[0]+p3[1])+(p3[2]+p3[3]))+((p3[4]+p3[5])+(p3[6]+p3[7]));
      float ghr = ((p4[0]+p4[1])+(p4[2]+p4[3]))+((p4[4]+p4[5])+(p4[6]+p4[7]));
      float ghh = ((p5[0]+p5[1])+(p5[2]+p5[3]))+((p5[4]+p5[5])+(p5[6]+p5[7]));
      float z  = fast_sig(gxz + ghz);
      float r  = fast_sig(gxr + ghr);
      float ht = fast_tanh(gxh + r*ghh);
      float hn = (1.0f - z)*h_lds[g] + z*ht;
      h_lds[g] = hn;
      out[((long)b*SN + s)*FN + g] = hn;
    }
    __syncthreads();                                    // bar7
    #pragma unroll
    for (int k = 0; k < 8; k++) xcur[k] = xnxt[k];
  }
#undef ISSUE_X
}

extern "C" void kernel_launch(void* const* d_in, const int* in_sizes, int n_in,
                              void* d_out, int out_size, void* d_ws, size_t ws_size,
                              hipStream_t stream)
{
  const float* x  = (const float*)d_in[0];
  const float* W  = (const float*)d_in[1];
  const float* Wc = (const float*)d_in[2];
  const float* bb = (const float*)d_in[3];
  const float* u  = (const float*)d_in[4];
  const float* Wx = (const float*)d_in[5];
  const float* Wh = (const float*)d_in[6];
  const float* bg = (const float*)d_in[7];
  float* out = (float*)d_out;
  float* xwbuf = (float*)d_ws;   // needs B*S*T*F*4 = 209,715,200 bytes

  k_xw  <<<dim3((BN*SN*TN) / 256), dim3(256), 0, stream>>>(x, W, bb, xwbuf);
  k_scan<<<dim3(BN), dim3(1024), 0, stream>>>(x, xwbuf, Wc, u, Wx, Wh, bg, out);
}